// Round 3
// baseline (331.597 us; speedup 1.0000x reference)
//
#include <hip/hip_runtime.h>
#include <hip/hip_cooperative_groups.h>
namespace cg = cooperative_groups;

#define BB 2
#define LL 1024
#define DD 1024
#define HH 16
#define NC 16
#define EPSF 1e-8f

typedef __attribute__((ext_vector_type(8))) short bf16x8;
typedef __attribute__((ext_vector_type(4))) float f32x4;
typedef unsigned short u16;

static __device__ inline u16 f2bf(float f) {
    unsigned int u = __builtin_bit_cast(unsigned int, f);
    u += 0x7fff + ((u >> 16) & 1);     // RNE
    return (u16)(u >> 16);
}
static __device__ inline float bf2f(u16 v) {
    unsigned int u = ((unsigned int)v) << 16;
    return __builtin_bit_cast(float, u);
}
static __device__ inline void gload_lds16(const u16* g, u16* l) {
    __builtin_amdgcn_global_load_lds((const __attribute__((address_space(1))) void*)g,
                                     (__attribute__((address_space(3))) void*)l, 16, 0, 0);
}

// ONE cooperative kernel, 512 blocks x 256 threads (2 blocks/CU resident):
//   phase 0: fp32->bf16 convert (grid-stride, 24 MB HBM-bound)
//   phase 1: bf16 MFMA GEMM (128x64 tile, BK=64 double-buffered, XOR swizzle)
//            + fused RMSNorm + per-chunk S_c^T = V_c^T K_c epilogue (V path)
//   phase 2: out = tril(QK^T)V + Q S0 with per-block bf16 prefix of S tiles
// Phases separated by __threadfence() + grid.sync() (device-scope release:
// cross-XCD L2 visibility that kernel boundaries previously provided).
__global__ __launch_bounds__(256, 2) void fused_all(
    const float* __restrict__ X, const float* __restrict__ Wq, const float* __restrict__ Wv,
    const float* __restrict__ qw, const float* __restrict__ vw,
    u16* __restrict__ Xb, u16* __restrict__ Wqb, u16* __restrict__ Wvb,
    u16* __restrict__ Qb, u16* __restrict__ Vb, u16* __restrict__ S,
    float* __restrict__ out)
{
    __shared__ alignas(16) char smem[49152];
    const int tid = threadIdx.x;
    const int bid = blockIdx.x;
    const int w = tid >> 6, lane = tid & 63;
    const int quad = lane >> 4, l16 = lane & 15;

    // ================= phase 0: convert =================
    {
        const int base = (bid * 256 + tid) * 4;
        #pragma unroll
        for (int it = 0; it < 8; ++it) {
            int i = base + it * (512 * 256 * 4);
            const float* s; u16* d; int off;
            if (i < 2*1024*1024)      { s = X;  d = Xb;  off = i; }
            else if (i < 3*1024*1024) { s = Wq; d = Wqb; off = i - 2*1024*1024; }
            else                      { s = Wv; d = Wvb; off = i - 3*1024*1024; }
            float4 v = *(const float4*)(s + off);
            ushort4 o;
            o.x = f2bf(v.x); o.y = f2bf(v.y); o.z = f2bf(v.z); o.w = f2bf(v.w);
            *(ushort4*)(d + off) = o;
        }
    }
    __threadfence();
    cg::this_grid().sync();

    // ================= phase 1: GEMM + RMSNorm + S epilogue =================
    {
        const int K = DD, N = DD;
        const int z = bid >> 8;
        const int m0 = ((bid >> 4) & 15) * 128, n0 = (bid & 15) * 64;
        const u16* W = z ? Wvb : Wqb;
        const float* nw = z ? vw : qw;
        u16* Y = z ? Vb : Qb;

        u16* Ab = (u16*)smem;                 // [2][128*64]  (32768 B)
        u16* Bb = (u16*)(smem + 32768);       // [2][64*64]   (16384 B)

        // staging: per gload call, lane -> row (lane>>3), phys chunk (lane&7).
        // source logical chunk = (lane&7) ^ (row&7) = (lane&7) ^ (lane>>3).
        const int lr8 = lane >> 3;
        const int lc8 = (lane & 7) ^ lr8;
        const u16* gA = Xb + (size_t)(m0 + w*32 + lr8) * K + lc8 * 8;
        const u16* gB = W  + (size_t)(n0 + w*16 + lr8) * K + lc8 * 8;

        f32x4 acc[2][4] = {};

        auto stage = [&](int buf, int k0) {
            u16* As = Ab + buf * (128*64);
            u16* Bs = Bb + buf * (64*64);
            #pragma unroll
            for (int q = 0; q < 4; ++q)
                gload_lds16(gA + k0 + (size_t)q*8*K, As + (w*32 + q*8)*64);
            #pragma unroll
            for (int q = 0; q < 2; ++q)
                gload_lds16(gB + k0 + (size_t)q*8*K, Bs + (w*16 + q*8)*64);
        };
        auto compute = [&](int buf) {
            const u16* As = Ab + buf * (128*64);
            const u16* Bs = Bb + buf * (64*64);
            #pragma unroll
            for (int hh = 0; hh < 2; ++hh) {
                const int co = (((hh << 2) | quad) ^ (l16 & 7)) * 8;
                bf16x8 af[2], bfr[4];
                #pragma unroll
                for (int i = 0; i < 2; ++i)
                    af[i] = *(const bf16x8*)&As[(w*32 + i*16 + l16) * 64 + co];
                #pragma unroll
                for (int j = 0; j < 4; ++j)
                    bfr[j] = *(const bf16x8*)&Bs[(j*16 + l16) * 64 + co];
                #pragma unroll
                for (int i = 0; i < 2; ++i)
                    #pragma unroll
                    for (int j = 0; j < 4; ++j)
                        acc[i][j] = __builtin_amdgcn_mfma_f32_16x16x32_bf16(af[i], bfr[j], acc[i][j], 0, 0, 0);
            }
        };

        stage(0, 0);
        __syncthreads();
        int cur = 0;
        for (int k0 = 0; k0 < K; k0 += 64) {
            if (k0 + 64 < K) stage(cur ^ 1, k0 + 64);
            compute(cur);
            __syncthreads();
            cur ^= 1;
        }

        // epilogue LDS union (A/B buffers dead past final barrier)
        u16 (*Vt)[136] = (u16 (*)[136])smem;            // [64][136]
        u16 (*Kt)[136] = (u16 (*)[136])(smem + 17408);  // [64][136]

        float wv4[4];
        #pragma unroll
        for (int j = 0; j < 4; ++j) wv4[j] = nw[n0 + j*16 + l16];
        #pragma unroll
        for (int i = 0; i < 2; ++i) {
            float ss[4];
            #pragma unroll
            for (int r = 0; r < 4; ++r) {
                float s = 0.f;
                #pragma unroll
                for (int j = 0; j < 4; ++j) s += acc[i][j][r] * acc[i][j][r];
                ss[r] = s;
            }
            #pragma unroll
            for (int off = 1; off < 16; off <<= 1)
                #pragma unroll
                for (int r = 0; r < 4; ++r) ss[r] += __shfl_xor(ss[r], off, 64);
            float sc[4];
            #pragma unroll
            for (int r = 0; r < 4; ++r) sc[r] = rsqrtf(ss[r] * (1.f/64.f) + EPSF);
            #pragma unroll
            for (int r = 0; r < 4; ++r) {
                u16* yp = Y + (size_t)(m0 + w*32 + i*16 + quad*4 + r) * N + n0;
                #pragma unroll
                for (int j = 0; j < 4; ++j) {
                    u16 val = f2bf(acc[i][j][r] * sc[r] * wv4[j]);
                    yp[j*16 + l16] = val;
                    if (z)
                        Vt[j*16 + l16][w*32 + i*16 + quad*4 + r] = val;
                }
            }
        }

        if (z) {
            {   // stage K tile (Xb rows m0..m0+127, this head's 64 cols), transposed
                const int row = tid >> 1, q2 = tid & 1;
                size_t gb = (size_t)(m0 + row) * DD + n0 + q2 * 32;
                u16 kk[32];
                #pragma unroll
                for (int i2 = 0; i2 < 32; i2 += 4)
                    *(ushort4*)&kk[i2] = *(const ushort4*)(Xb + gb + i2);
                #pragma unroll
                for (int i2 = 0; i2 < 32; ++i2)
                    Kt[q2*32 + i2][row] = kk[i2];
            }
            __syncthreads();
            const int me = (w & 1) * 32, nd = (w >> 1) * 32;
            const int bb_ = m0 >> 10, c0 = (m0 & 1023) >> 6, h = bid & 15;
            const int bh = bb_ * HH + h;
            #pragma unroll
            for (int cc = 0; cc < 2; ++cc) {
                f32x4 sacc[2][2] = {};
                #pragma unroll
                for (int k0 = 0; k0 < 64; k0 += 32) {
                    bf16x8 av[2], bv[2];
                    #pragma unroll
                    for (int i2 = 0; i2 < 2; ++i2)
                        av[i2] = *(const bf16x8*)&Vt[me + i2*16 + l16][cc*64 + k0 + quad*8];
                    #pragma unroll
                    for (int j2 = 0; j2 < 2; ++j2)
                        bv[j2] = *(const bf16x8*)&Kt[nd + j2*16 + l16][cc*64 + k0 + quad*8];
                    #pragma unroll
                    for (int i2 = 0; i2 < 2; ++i2)
                        #pragma unroll
                        for (int j2 = 0; j2 < 2; ++j2)
                            sacc[i2][j2] = __builtin_amdgcn_mfma_f32_16x16x32_bf16(av[i2], bv[j2], sacc[i2][j2], 0, 0, 0);
                }
                u16* Sp = S + ((size_t)((bh << 4) | (c0 + cc)) << 12) + w*1024;
                #pragma unroll
                for (int i2 = 0; i2 < 2; ++i2)
                    #pragma unroll
                    for (int j2 = 0; j2 < 2; ++j2)
                        #pragma unroll
                        for (int r = 0; r < 4; ++r)
                            Sp[(i2*2 + j2)*256 + r*64 + lane] = f2bf(sacc[i2][j2][r]);
            }
        }
    }
    __syncthreads();
    __threadfence();
    cg::this_grid().sync();

    // ================= phase 2: output =================
    {
        const int c = 15 - (bid & 15);   // chunk
        const int bh = bid >> 4;
        const int h = bh & 15, b = bh >> 4;
        u16 (*Qs)[72] = (u16 (*)[72])smem;                // [64][72]
        u16 (*Ks)[72] = (u16 (*)[72])(smem + 9216);       // [64][72] -> later P
        u16 (*Vt)[72] = (u16 (*)[72])(smem + 18432);      // [64][72]
        u16 (*St)[72] = (u16 (*)[72])(smem + 27648);      // [64][72]
        {
            const int row = tid >> 2, q = tid & 3;
            size_t gbase = (size_t)(b*LL + c*64 + row) * DD + h*64 + q*16;
            u16 vv[16];
            #pragma unroll
            for (int i = 0; i < 16; i += 4) {
                *(ushort4*)&Qs[row][q*16 + i] = *(const ushort4*)(Qb + gbase + i);
                *(ushort4*)&Ks[row][q*16 + i] = *(const ushort4*)(Xb + gbase + i);
                *(ushort4*)&vv[i] = *(const ushort4*)(Vb + gbase + i);
            }
            #pragma unroll
            for (int i = 0; i < 16; ++i)
                Vt[q*16 + i][row] = vv[i];
            // prefix sum of earlier chunk tiles, unrolled x4 for load ILP
            float facc[16] = {};
            const u16* Sbase = S + ((size_t)(bh * NC) << 12);
            int cp = 0;
            for (; cp + 4 <= c; cp += 4) {
                ushort4 sv[4][4];
                #pragma unroll
                for (int u = 0; u < 4; ++u)
                    #pragma unroll
                    for (int jj = 0; jj < 4; ++jj)
                        sv[u][jj] = *(const ushort4*)(Sbase + ((size_t)(cp + u) << 12) + tid*4 + jj*1024);
                #pragma unroll
                for (int u = 0; u < 4; ++u)
                    #pragma unroll
                    for (int jj = 0; jj < 4; ++jj) {
                        facc[jj*4+0] += bf2f(sv[u][jj].x);
                        facc[jj*4+1] += bf2f(sv[u][jj].y);
                        facc[jj*4+2] += bf2f(sv[u][jj].z);
                        facc[jj*4+3] += bf2f(sv[u][jj].w);
                    }
            }
            for (; cp < c; ++cp) {
                const u16* Sc = Sbase + ((size_t)cp << 12);
                #pragma unroll
                for (int jj = 0; jj < 4; ++jj) {
                    ushort4 sv = *(const ushort4*)(Sc + tid*4 + jj*1024);
                    facc[jj*4+0] += bf2f(sv.x);
                    facc[jj*4+1] += bf2f(sv.y);
                    facc[jj*4+2] += bf2f(sv.z);
                    facc[jj*4+3] += bf2f(sv.w);
                }
            }
            // decode flat C-layout and write St[e][d..d+3]
            #pragma unroll
            for (int jj = 0; jj < 4; ++jj) {
                int g = tid * 4;
                int ij = (g >> 8) & 3, r = (g >> 6) & 3, ln = g & 63;
                int e = (jj & 1)*32 + (ij >> 1)*16 + (ln >> 4)*4 + r;
                int d = (jj >> 1)*32 + (ij & 1)*16 + (ln & 15);
                ushort4 o;
                o.x = f2bf(facc[jj*4+0]);
                o.y = f2bf(facc[jj*4+1]);
                o.z = f2bf(facc[jj*4+2]);
                o.w = f2bf(facc[jj*4+3]);
                *(ushort4*)&St[e][d] = o;
            }
        }
        __syncthreads();
        const int mo = (w & 1) * 32, no = (w >> 1) * 32;

        // P = Q K^T, causal-masked, bf16 (P aliases Ks)
        f32x4 pacc[2][2] = {};
        #pragma unroll
        for (int k0 = 0; k0 < 64; k0 += 32) {
            bf16x8 aq[2], bk[2];
            #pragma unroll
            for (int i = 0; i < 2; ++i)
                aq[i] = *(const bf16x8*)&Qs[mo + i*16 + l16][k0 + quad*8];
            #pragma unroll
            for (int j = 0; j < 2; ++j)
                bk[j] = *(const bf16x8*)&Ks[no + j*16 + l16][k0 + quad*8];
            #pragma unroll
            for (int i = 0; i < 2; ++i)
                #pragma unroll
                for (int j = 0; j < 2; ++j)
                    pacc[i][j] = __builtin_amdgcn_mfma_f32_16x16x32_bf16(aq[i], bk[j], pacc[i][j], 0, 0, 0);
        }
        __syncthreads();
        #pragma unroll
        for (int i = 0; i < 2; ++i)
            #pragma unroll
            for (int j = 0; j < 2; ++j)
                #pragma unroll
                for (int r = 0; r < 4; ++r) {
                    int l  = mo + i*16 + quad*4 + r;
                    int lp = no + j*16 + l16;
                    Ks[l][lp] = (lp <= l) ? f2bf(pacc[i][j][r]) : (u16)0;
                }
        __syncthreads();

        // O = P @ V + Q @ S0
        f32x4 acc[2][2] = {};
        #pragma unroll
        for (int k0 = 0; k0 < 64; k0 += 32) {
            bf16x8 a1[2], b1[2], a2[2], b2[2];
            #pragma unroll
            for (int i = 0; i < 2; ++i) {
                a1[i] = *(const bf16x8*)&Ks[mo + i*16 + l16][k0 + quad*8];
                a2[i] = *(const bf16x8*)&Qs[mo + i*16 + l16][k0 + quad*8];
            }
            #pragma unroll
            for (int j = 0; j < 2; ++j) {
                b1[j] = *(const bf16x8*)&Vt[no + j*16 + l16][k0 + quad*8];
                b2[j] = *(const bf16x8*)&St[no + j*16 + l16][k0 + quad*8];
            }
            #pragma unroll
            for (int i = 0; i < 2; ++i)
                #pragma unroll
                for (int j = 0; j < 2; ++j) {
                    acc[i][j] = __builtin_amdgcn_mfma_f32_16x16x32_bf16(a1[i], b1[j], acc[i][j], 0, 0, 0);
                    acc[i][j] = __builtin_amdgcn_mfma_f32_16x16x32_bf16(a2[i], b2[j], acc[i][j], 0, 0, 0);
                }
        }
        float* op = out + (size_t)(b*LL + c*64) * DD + h*64;
        #pragma unroll
        for (int i = 0; i < 2; ++i)
            #pragma unroll
            for (int j = 0; j < 2; ++j)
                #pragma unroll
                for (int r = 0; r < 4; ++r)
                    op[(size_t)(mo + i*16 + quad*4 + r) * DD + no + j*16 + l16] = acc[i][j][r];
    }
}

extern "C" void kernel_launch(void* const* d_in, const int* in_sizes, int n_in,
                              void* d_out, int out_size, void* d_ws, size_t ws_size,
                              hipStream_t stream) {
    const float* X  = (const float*)d_in[0];
    const float* Wq = (const float*)d_in[1];
    const float* Wv = (const float*)d_in[2];
    const float* qw = (const float*)d_in[3];
    const float* vw = (const float*)d_in[4];
    float* out = (float*)d_out;

    u16* Xb  = (u16*)d_ws;                        // 2M u16
    u16* Wqb = Xb  + (size_t)2*1024*1024;         // 1M
    u16* Wvb = Wqb + (size_t)1024*1024;           // 1M
    u16* Qb  = Wvb + (size_t)1024*1024;           // 2M
    u16* Vb  = Qb  + (size_t)2*1024*1024;         // 2M
    u16* S   = Vb  + (size_t)2*1024*1024;         // 2M u16

    void* args[12];
    args[0]  = (void*)&X;   args[1]  = (void*)&Wq;  args[2]  = (void*)&Wv;
    args[3]  = (void*)&qw;  args[4]  = (void*)&vw;
    args[5]  = (void*)&Xb;  args[6]  = (void*)&Wqb; args[7]  = (void*)&Wvb;
    args[8]  = (void*)&Qb;  args[9]  = (void*)&Vb;  args[10] = (void*)&S;
    args[11] = (void*)&out;
    hipLaunchCooperativeKernel((const void*)fused_all, dim3(512), dim3(256), args, 0, stream);
}

// Round 4
// 98.050 us; speedup vs baseline: 3.3819x; 3.3819x over previous
//
#include <hip/hip_runtime.h>

#define BB 2
#define LL 1024
#define DD 1024
#define HH 16
#define NC 16
#define EPSF 1e-8f

typedef __attribute__((ext_vector_type(8))) short bf16x8;
typedef __attribute__((ext_vector_type(4))) float f32x4;
typedef unsigned short u16;

static __device__ inline u16 f2bf(float f) {
    unsigned int u = __builtin_bit_cast(unsigned int, f);
    u += 0x7fff + ((u >> 16) & 1);     // RNE
    return (u16)(u >> 16);
}
static __device__ inline float bf2f(u16 v) {
    unsigned int u = ((unsigned int)v) << 16;
    return __builtin_bit_cast(float, u);
}
static __device__ inline void gload_lds16(const u16* g, u16* l) {
    __builtin_amdgcn_global_load_lds((const __attribute__((address_space(1))) void*)g,
                                     (__attribute__((address_space(3))) void*)l, 16, 0, 0);
}

// ---------------- fp32 -> bf16 convert: X (2M), Wq (1M), Wv (1M)
__global__ __launch_bounds__(256) void cvt_k(const float* __restrict__ X,
                                             const float* __restrict__ Wq,
                                             const float* __restrict__ Wv,
                                             u16* __restrict__ Xb,
                                             u16* __restrict__ Wqb,
                                             u16* __restrict__ Wvb)
{
    int i = (blockIdx.x * 256 + threadIdx.x) * 4;
    const float* s; u16* d; int off;
    if (i < 2*1024*1024)      { s = X;  d = Xb;  off = i; }
    else if (i < 3*1024*1024) { s = Wq; d = Wqb; off = i - 2*1024*1024; }
    else                      { s = Wv; d = Wvb; off = i - 3*1024*1024; }
    float4 v = *(const float4*)(s + off);
    ushort4 o;
    o.x = f2bf(v.x); o.y = f2bf(v.y); o.z = f2bf(v.z); o.w = f2bf(v.w);
    *(ushort4*)(d + off) = o;
}

// ---------------- bf16 MFMA GEMM + fused per-head RMSNorm, bf16 out.
// 128(M) x 64(N) tile, BK=64, double-buffered (1 barrier per K-step).
// XOR chunk swizzle on both gload-source and ds_read (rule #21).
// T1 XCD-chunked blockIdx swizzle: nb=(bid%8)*64+bid/8 (bijective, 512=8*64)
// gives each XCD {one z, 4 m-tiles, all 16 n} -> A(1MB)+W(2MB) = 3MB < 4MB L2
// (unswizzled round-robin working set was 4.5MB > L2 -> A re-reads hit L3).
// Epilogue (V path) computes per-chunk S_c^T = V_c^T K_c, LDS unioned.
__global__ __launch_bounds__(256) void gemm_fused(const u16* __restrict__ Xb,
                                                  const u16* __restrict__ Wqb,
                                                  const u16* __restrict__ Wvb,
                                                  const float* __restrict__ qw,
                                                  const float* __restrict__ vw,
                                                  u16* __restrict__ Qb,
                                                  u16* __restrict__ Vb,
                                                  u16* __restrict__ S)
{
    const int K = DD, N = DD;
    const int nb = (blockIdx.x & 7) * 64 + (blockIdx.x >> 3);   // XCD chunk swizzle
    const int z = nb >> 8;
    const int m0 = ((nb >> 4) & 15) * 128, n0 = (nb & 15) * 64;
    const u16* W = z ? Wvb : Wqb;
    const float* nw = z ? vw : qw;
    u16* Y = z ? Vb : Qb;

    __shared__ alignas(16) char smem[49152];
    u16* Ab = (u16*)smem;                 // [2][128*64]  (32768 B)
    u16* Bb = (u16*)(smem + 32768);       // [2][64*64]   (16384 B)

    const int tid = threadIdx.x, w = tid >> 6, lane = tid & 63;
    const int quad = lane >> 4, l16 = lane & 15;

    // staging: per gload call, lane -> row (lane>>3), phys chunk (lane&7).
    // source logical chunk = (lane&7) ^ (row&7) = (lane&7) ^ (lane>>3).
    const int lr8 = lane >> 3;
    const int lc8 = (lane & 7) ^ lr8;
    const u16* gA = Xb + (size_t)(m0 + w*32 + lr8) * K + lc8 * 8;
    const u16* gB = W  + (size_t)(n0 + w*16 + lr8) * K + lc8 * 8;

    f32x4 acc[2][4] = {};

    auto stage = [&](int buf, int k0) {
        u16* As = Ab + buf * (128*64);
        u16* Bs = Bb + buf * (64*64);
        #pragma unroll
        for (int q = 0; q < 4; ++q)
            gload_lds16(gA + k0 + (size_t)q*8*K, As + (w*32 + q*8)*64);
        #pragma unroll
        for (int q = 0; q < 2; ++q)
            gload_lds16(gB + k0 + (size_t)q*8*K, Bs + (w*16 + q*8)*64);
    };
    auto compute = [&](int buf) {
        const u16* As = Ab + buf * (128*64);
        const u16* Bs = Bb + buf * (64*64);
        #pragma unroll
        for (int hh = 0; hh < 2; ++hh) {
            const int co = (((hh << 2) | quad) ^ (l16 & 7)) * 8;
            bf16x8 af[2], bfr[4];
            #pragma unroll
            for (int i = 0; i < 2; ++i)
                af[i] = *(const bf16x8*)&As[(w*32 + i*16 + l16) * 64 + co];
            #pragma unroll
            for (int j = 0; j < 4; ++j)
                bfr[j] = *(const bf16x8*)&Bs[(j*16 + l16) * 64 + co];
            #pragma unroll
            for (int i = 0; i < 2; ++i)
                #pragma unroll
                for (int j = 0; j < 4; ++j)
                    acc[i][j] = __builtin_amdgcn_mfma_f32_16x16x32_bf16(af[i], bfr[j], acc[i][j], 0, 0, 0);
        }
    };

    stage(0, 0);
    __syncthreads();
    int cur = 0;
    for (int k0 = 0; k0 < K; k0 += 64) {
        if (k0 + 64 < K) stage(cur ^ 1, k0 + 64);
        compute(cur);
        __syncthreads();
        cur ^= 1;
    }

    // epilogue LDS union (A/B buffers dead past final barrier)
    u16 (*Vt)[136] = (u16 (*)[136])smem;            // [64][136]
    u16 (*Kt)[136] = (u16 (*)[136])(smem + 17408);  // [64][136]

    float wv4[4];
    #pragma unroll
    for (int j = 0; j < 4; ++j) wv4[j] = nw[n0 + j*16 + l16];
    #pragma unroll
    for (int i = 0; i < 2; ++i) {
        float ss[4];
        #pragma unroll
        for (int r = 0; r < 4; ++r) {
            float s = 0.f;
            #pragma unroll
            for (int j = 0; j < 4; ++j) s += acc[i][j][r] * acc[i][j][r];
            ss[r] = s;
        }
        #pragma unroll
        for (int off = 1; off < 16; off <<= 1)
            #pragma unroll
            for (int r = 0; r < 4; ++r) ss[r] += __shfl_xor(ss[r], off, 64);
        float sc[4];
        #pragma unroll
        for (int r = 0; r < 4; ++r) sc[r] = rsqrtf(ss[r] * (1.f/64.f) + EPSF);
        #pragma unroll
        for (int r = 0; r < 4; ++r) {
            u16* yp = Y + (size_t)(m0 + w*32 + i*16 + quad*4 + r) * N + n0;
            #pragma unroll
            for (int j = 0; j < 4; ++j) {
                u16 val = f2bf(acc[i][j][r] * sc[r] * wv4[j]);
                yp[j*16 + l16] = val;
                if (z)
                    Vt[j*16 + l16][w*32 + i*16 + quad*4 + r] = val;
            }
        }
    }

    // ---------- fused per-chunk S epilogue (V path only) ----------
    if (z) {
        {   // stage K tile (Xb rows m0..m0+127, this head's 64 cols), transposed
            const int row = tid >> 1, q2 = tid & 1;
            size_t gb = (size_t)(m0 + row) * DD + n0 + q2 * 32;
            u16 kk[32];
            #pragma unroll
            for (int i2 = 0; i2 < 32; i2 += 4)
                *(ushort4*)&kk[i2] = *(const ushort4*)(Xb + gb + i2);
            #pragma unroll
            for (int i2 = 0; i2 < 32; ++i2)
                Kt[q2*32 + i2][row] = kk[i2];
        }
        __syncthreads();
        const int me = (w & 1) * 32, nd = (w >> 1) * 32;
        const int bb_ = m0 >> 10, c0 = (m0 & 1023) >> 6, h = nb & 15;
        const int bh = bb_ * HH + h;
        #pragma unroll
        for (int cc = 0; cc < 2; ++cc) {
            f32x4 sacc[2][2] = {};
            #pragma unroll
            for (int k0 = 0; k0 < 64; k0 += 32) {
                bf16x8 av[2], bv[2];
                #pragma unroll
                for (int i2 = 0; i2 < 2; ++i2)
                    av[i2] = *(const bf16x8*)&Vt[me + i2*16 + l16][cc*64 + k0 + quad*8];
                #pragma unroll
                for (int j2 = 0; j2 < 2; ++j2)
                    bv[j2] = *(const bf16x8*)&Kt[nd + j2*16 + l16][cc*64 + k0 + quad*8];
                #pragma unroll
                for (int i2 = 0; i2 < 2; ++i2)
                    #pragma unroll
                    for (int j2 = 0; j2 < 2; ++j2)
                        sacc[i2][j2] = __builtin_amdgcn_mfma_f32_16x16x32_bf16(av[i2], bv[j2], sacc[i2][j2], 0, 0, 0);
            }
            // same flat C-layout + tile indexing as the former kv_chunk kernel
            u16* Sp = S + ((size_t)((bh << 4) | (c0 + cc)) << 12) + w*1024;
            #pragma unroll
            for (int i2 = 0; i2 < 2; ++i2)
                #pragma unroll
                for (int j2 = 0; j2 < 2; ++j2)
                    #pragma unroll
                    for (int r = 0; r < 4; ++r)
                        Sp[(i2*2 + j2)*256 + r*64 + lane] = f2bf(sacc[i2][j2][r]);
        }
    }
}

// ---------------- out = tril(Q K^T) @ V + Q @ S0; block sums its own prefix
// from the parallel per-chunk S tiles. T1 XCD chunk swizzle keeps all 16
// chunk-blocks of a (b,h) (sharing its 128 KB S prefix) on one XCD's L2.
__global__ __launch_bounds__(256) void out_k2(const u16* __restrict__ Xb,
                                              const u16* __restrict__ Qb,
                                              const u16* __restrict__ Vb,
                                              const u16* __restrict__ S,
                                              float* __restrict__ out)
{
    const int nb = (blockIdx.x & 7) * 64 + (blockIdx.x >> 3);   // XCD chunk swizzle
    const int c = 15 - (nb & 15);   // heavy (large-c) blocks first within chunk
    const int bh = nb >> 4;
    const int h = bh & 15, b = bh >> 4;
    __shared__ u16 Qs[64][72];   // [l][d]
    __shared__ u16 Ks[64][72];   // [l'][d] -> later Ps [l][l']
    __shared__ u16 Vt[64][72];   // [e][l']
    __shared__ u16 St[64][72];   // [e][d]  summed prefix, bf16
    const int tid = threadIdx.x;
    {
        const int row = tid >> 2, q = tid & 3;
        size_t gbase = (size_t)(b*LL + c*64 + row) * DD + h*64 + q*16;
        u16 vv[16];
        #pragma unroll
        for (int i = 0; i < 16; i += 4) {
            *(ushort4*)&Qs[row][q*16 + i] = *(const ushort4*)(Qb + gbase + i);
            *(ushort4*)&Ks[row][q*16 + i] = *(const ushort4*)(Xb + gbase + i);
            *(ushort4*)&vv[i] = *(const ushort4*)(Vb + gbase + i);
        }
        #pragma unroll
        for (int i = 0; i < 16; ++i)
            Vt[q*16 + i][row] = vv[i];
        // prefix sum of earlier chunk tiles, unrolled x4 for load ILP
        // (element-wise accumulation order preserved).
        float facc[16] = {};
        const u16* Sbase = S + ((size_t)(bh * NC) << 12);
        int cp = 0;
        for (; cp + 4 <= c; cp += 4) {
            ushort4 sv[4][4];
            #pragma unroll
            for (int u = 0; u < 4; ++u)
                #pragma unroll
                for (int jj = 0; jj < 4; ++jj)
                    sv[u][jj] = *(const ushort4*)(Sbase + ((size_t)(cp + u) << 12) + tid*4 + jj*1024);
            #pragma unroll
            for (int u = 0; u < 4; ++u)
                #pragma unroll
                for (int jj = 0; jj < 4; ++jj) {
                    facc[jj*4+0] += bf2f(sv[u][jj].x);
                    facc[jj*4+1] += bf2f(sv[u][jj].y);
                    facc[jj*4+2] += bf2f(sv[u][jj].z);
                    facc[jj*4+3] += bf2f(sv[u][jj].w);
                }
        }
        for (; cp < c; ++cp) {
            const u16* Sc = Sbase + ((size_t)cp << 12);
            #pragma unroll
            for (int jj = 0; jj < 4; ++jj) {
                ushort4 sv = *(const ushort4*)(Sc + tid*4 + jj*1024);
                facc[jj*4+0] += bf2f(sv.x);
                facc[jj*4+1] += bf2f(sv.y);
                facc[jj*4+2] += bf2f(sv.z);
                facc[jj*4+3] += bf2f(sv.w);
            }
        }
        // decode flat C-layout and write St[e][d..d+3]
        #pragma unroll
        for (int jj = 0; jj < 4; ++jj) {
            int g = tid * 4;                 // offset within the 1024-elem quadrant
            int ij = (g >> 8) & 3, r = (g >> 6) & 3, ln = g & 63;
            int e = (jj & 1)*32 + (ij >> 1)*16 + (ln >> 4)*4 + r;
            int d = (jj >> 1)*32 + (ij & 1)*16 + (ln & 15);
            ushort4 o;
            o.x = f2bf(facc[jj*4+0]);
            o.y = f2bf(facc[jj*4+1]);
            o.z = f2bf(facc[jj*4+2]);
            o.w = f2bf(facc[jj*4+3]);
            *(ushort4*)&St[e][d] = o;
        }
    }
    __syncthreads();
    const int w = tid >> 6, lane = tid & 63, quad = lane >> 4, l16 = lane & 15;
    const int mo = (w & 1) * 32, no = (w >> 1) * 32;

    // P = Q K^T, causal-masked, bf16 (P aliases Ks)
    f32x4 pacc[2][2] = {};
    #pragma unroll
    for (int k0 = 0; k0 < 64; k0 += 32) {
        bf16x8 aq[2], bk[2];
        #pragma unroll
        for (int i = 0; i < 2; ++i)
            aq[i] = *(const bf16x8*)&Qs[mo + i*16 + l16][k0 + quad*8];
        #pragma unroll
        for (int j = 0; j < 2; ++j)
            bk[j] = *(const bf16x8*)&Ks[no + j*16 + l16][k0 + quad*8];
        #pragma unroll
        for (int i = 0; i < 2; ++i)
            #pragma unroll
            for (int j = 0; j < 2; ++j)
                pacc[i][j] = __builtin_amdgcn_mfma_f32_16x16x32_bf16(aq[i], bk[j], pacc[i][j], 0, 0, 0);
    }
    __syncthreads();
    #pragma unroll
    for (int i = 0; i < 2; ++i)
        #pragma unroll
        for (int j = 0; j < 2; ++j)
            #pragma unroll
            for (int r = 0; r < 4; ++r) {
                int l  = mo + i*16 + quad*4 + r;
                int lp = no + j*16 + l16;
                Ks[l][lp] = (lp <= l) ? f2bf(pacc[i][j][r]) : (u16)0;
            }
    __syncthreads();

    // O = P @ V + Q @ S0
    f32x4 acc[2][2] = {};
    #pragma unroll
    for (int k0 = 0; k0 < 64; k0 += 32) {
        bf16x8 a1[2], b1[2], a2[2], b2[2];
        #pragma unroll
        for (int i = 0; i < 2; ++i) {
            a1[i] = *(const bf16x8*)&Ks[mo + i*16 + l16][k0 + quad*8];
            a2[i] = *(const bf16x8*)&Qs[mo + i*16 + l16][k0 + quad*8];
        }
        #pragma unroll
        for (int j = 0; j < 2; ++j) {
            b1[j] = *(const bf16x8*)&Vt[no + j*16 + l16][k0 + quad*8];
            b2[j] = *(const bf16x8*)&St[no + j*16 + l16][k0 + quad*8];
        }
        #pragma unroll
        for (int i = 0; i < 2; ++i)
            #pragma unroll
            for (int j = 0; j < 2; ++j) {
                acc[i][j] = __builtin_amdgcn_mfma_f32_16x16x32_bf16(a1[i], b1[j], acc[i][j], 0, 0, 0);
                acc[i][j] = __builtin_amdgcn_mfma_f32_16x16x32_bf16(a2[i], b2[j], acc[i][j], 0, 0, 0);
            }
    }
    float* op = out + (size_t)(b*LL + c*64) * DD + h*64;
    #pragma unroll
    for (int i = 0; i < 2; ++i)
        #pragma unroll
        for (int j = 0; j < 2; ++j)
            #pragma unroll
            for (int r = 0; r < 4; ++r)
                op[(size_t)(mo + i*16 + quad*4 + r) * DD + no + j*16 + l16] = acc[i][j][r];
}

extern "C" void kernel_launch(void* const* d_in, const int* in_sizes, int n_in,
                              void* d_out, int out_size, void* d_ws, size_t ws_size,
                              hipStream_t stream) {
    const float* X  = (const float*)d_in[0];
    const float* Wq = (const float*)d_in[1];
    const float* Wv = (const float*)d_in[2];
    const float* qw = (const float*)d_in[3];
    const float* vw = (const float*)d_in[4];
    float* out = (float*)d_out;

    u16* Xb  = (u16*)d_ws;                        // 2M u16
    u16* Wqb = Xb  + (size_t)2*1024*1024;         // 1M
    u16* Wvb = Wqb + (size_t)1024*1024;           // 1M
    u16* Qb  = Wvb + (size_t)1024*1024;           // 2M
    u16* Vb  = Qb  + (size_t)2*1024*1024;         // 2M
    u16* S   = Vb  + (size_t)2*1024*1024;         // 2M u16

    cvt_k<<<4096, 256, 0, stream>>>(X, Wq, Wv, Xb, Wqb, Wvb);
    gemm_fused<<<512, 256, 0, stream>>>(Xb, Wqb, Wvb, qw, vw, Qb, Vb, S);
    out_k2<<<512, 256, 0, stream>>>(Xb, Qb, Vb, S, out);
}